// Round 7
// baseline (1060.834 us; speedup 1.0000x reference)
//
#include <hip/hip_runtime.h>

#define N_NODES 100000
#define N_EDGES 1600000
#define HIDDEN 64
#define EDGE_DIM 16
#define N_LAYERS 3
#define N_GRAPHS 512
#define BN_EPS 1e-5f

#define CHUNK 2048
#define NCHUNK ((N_NODES + CHUNK - 1) / CHUNK)   // 49

#define BSHIFT 5
#define NBUCK (N_NODES >> BSHIFT)                // 3125 (exact: 100000 = 3125*32)
#define EMASK 0x07FFFFFF

typedef _Float16 h2 __attribute__((ext_vector_type(2)));
typedef _Float16 h4 __attribute__((ext_vector_type(4)));

// ---------------- CSR row_start construction ----------------

__global__ void k_hist(const int* __restrict__ dst, int* __restrict__ hist) {
    int e = blockIdx.x * 256 + threadIdx.x;
    if (e < N_EDGES) atomicAdd(&hist[dst[e]], 1);
}

__global__ void k_scan_partial(const int* __restrict__ hist, int* __restrict__ partial) {
    __shared__ int sd[256];
    int c = blockIdx.x, t = threadIdx.x;
    int base = c * CHUNK + t * 8;
    int s = 0;
#pragma unroll
    for (int u = 0; u < 8; ++u) {
        int i = base + u;
        s += (i < N_NODES) ? hist[i] : 0;
    }
    sd[t] = s;
    __syncthreads();
    for (int d = 128; d > 0; d >>= 1) {
        if (t < d) sd[t] += sd[t + d];
        __syncthreads();
    }
    if (t == 0) partial[c] = sd[0];
}

__global__ void k_scan_base(const int* __restrict__ partial, int* __restrict__ cbase) {
    if (threadIdx.x == 0) {
        int r = 0;
        for (int c = 0; c < NCHUNK; ++c) { cbase[c] = r; r += partial[c]; }
    }
}

__global__ void k_scan_final(const int* __restrict__ hist, const int* __restrict__ cbase,
                             int* __restrict__ row_start) {
    __shared__ int sd[256];
    int c = blockIdx.x, t = threadIdx.x;
    int i0 = c * CHUNK + t * 8;
    int v[8];
    int s = 0;
#pragma unroll
    for (int u = 0; u < 8; ++u) {
        int i = i0 + u;
        v[u] = (i < N_NODES) ? hist[i] : 0;
        s += v[u];
    }
    sd[t] = s;
    __syncthreads();
    for (int d = 1; d < 256; d <<= 1) {
        int x = (t >= d) ? sd[t - d] : 0;
        __syncthreads();
        sd[t] += x;
        __syncthreads();
    }
    int run = cbase[c] + sd[t] - s;  // exclusive prefix for this thread
#pragma unroll
    for (int u = 0; u < 8; ++u) {
        int i = i0 + u;
        if (i <= N_NODES) row_start[i] = run;
        run += v[u];
    }
}

// ---------------- bucketed (localized) edge sort ----------------

// count edges per coarse bucket (dst>>5) via LDS sub-histogram
__global__ __launch_bounds__(256) void k_bcount(const int* __restrict__ dst,
                                                int* __restrict__ bcount) {
    __shared__ int lh[NBUCK];
    for (int i = threadIdx.x; i < NBUCK; i += 256) lh[i] = 0;
    __syncthreads();
    int tid = blockIdx.x * 256 + threadIdx.x;
    for (int e = tid; e < N_EDGES; e += gridDim.x * 256)
        atomicAdd(&lh[dst[e] >> BSHIFT], 1);
    __syncthreads();
    for (int i = threadIdx.x; i < NBUCK; i += 256) {
        int v = lh[i];
        if (v) atomicAdd(&bcount[i], v);
    }
}

// exclusive scan of 3125 bucket counts (single block)
__global__ __launch_bounds__(256) void k_bscan(const int* __restrict__ bcount,
                                               int* __restrict__ bstart, int* __restrict__ bcur) {
    __shared__ int sd[256];
    const int PER = (NBUCK + 255) / 256;   // 13
    int t = threadIdx.x;
    int base = t * PER;
    int s = 0;
#pragma unroll
    for (int u = 0; u < PER; ++u) {
        int i = base + u;
        if (i < NBUCK) s += bcount[i];
    }
    sd[t] = s;
    __syncthreads();
    for (int d = 1; d < 256; d <<= 1) {
        int x = (t >= d) ? sd[t - d] : 0;
        __syncthreads();
        sd[t] += x;
        __syncthreads();
    }
    int run = sd[t] - s;   // exclusive
#pragma unroll
    for (int u = 0; u < PER; ++u) {
        int i = base + u;
        if (i < NBUCK) {
            bstart[i] = run;
            bcur[i] = run;
            run += bcount[i];
        }
    }
    if (t == 255) bstart[NBUCK] = N_EDGES;
}

// scatter {e, src} into per-bucket regions (4KB windows -> localized writes)
__global__ void k_bscatter(const int* __restrict__ edge_index, int* __restrict__ bcur,
                           int2* __restrict__ brec) {
    int e = blockIdx.x * 256 + threadIdx.x;
    if (e >= N_EDGES) return;
    int s = edge_index[e];
    int d = edge_index[N_EDGES + e];
    int pos = atomicAdd(&bcur[d >> BSHIFT], 1);
    brec[pos] = make_int2(e | ((d & 31) << 27), s);
}

// block-per-bucket: exact CSR ranking via 32 LDS counters (bucket = contiguous
// dst range, so local rank == global rank), then fused gather: random 64B ea
// read -> f16 -> write into the bucket's contiguous ea16 window (full-line).
__global__ __launch_bounds__(256) void k_bfinal(const int2* __restrict__ brec,
        const int* __restrict__ bstart, const int* __restrict__ row_start,
        const float* __restrict__ ea, _Float16* __restrict__ ea16,
        int* __restrict__ src_sorted) {
    __shared__ int cnt[32];
    int b = blockIdx.x;
    if (threadIdx.x < 32) cnt[threadIdx.x] = 0;
    __syncthreads();
    int r0 = bstart[b], r1 = bstart[b + 1];
    for (int i = r0 + threadIdx.x; i < r1; i += 256) {
        int2 rec = brec[i];
        int e = rec.x & EMASK;
        int lo5 = (unsigned)rec.x >> 27;
        int dst = (b << BSHIFT) | lo5;
        int rank = atomicAdd(&cnt[lo5], 1);
        int p = row_start[dst] + rank;
        const float4* er = (const float4*)(ea + (size_t)e * 16);
        float4 v0 = er[0], v1 = er[1], v2 = er[2], v3 = er[3];
        h4* op = (h4*)(ea16 + (size_t)p * 16);
        h4 o0 = {(_Float16)v0.x, (_Float16)v0.y, (_Float16)v0.z, (_Float16)v0.w};
        h4 o1 = {(_Float16)v1.x, (_Float16)v1.y, (_Float16)v1.z, (_Float16)v1.w};
        h4 o2 = {(_Float16)v2.x, (_Float16)v2.y, (_Float16)v2.z, (_Float16)v2.w};
        h4 o3 = {(_Float16)v3.x, (_Float16)v3.y, (_Float16)v3.z, (_Float16)v3.w};
        op[0] = o0; op[1] = o1; op[2] = o2; op[3] = o3;
        src_sorted[p] = rec.y;
    }
}

// x (f32, [N,64]) -> x16 (f16 compact copy) for the gather path
__global__ __launch_bounds__(256) void k_cvt_x(const float* __restrict__ x,
                                               _Float16* __restrict__ x16) {
    int i = blockIdx.x * 256 + threadIdx.x;   // float4 units, N*16 total
    if (i >= N_NODES * 16) return;
    float4 v = ((const float4*)x)[i];
    h4 o = {(_Float16)v.x, (_Float16)v.y, (_Float16)v.z, (_Float16)v.w};
    ((h4*)x16)[i] = o;
}

// ---------------- per-layer kernels ----------------

// wave-per-node edge aggregation:
//   hin[n][j] = zself[n][j] + sum_p relu(z16[src[p]][j] + dot(ea16[p], We[:,j]) + be[j])
__global__ __launch_bounds__(256) void k_aggregate(
        const float* __restrict__ zself_base, int zstride,
        const _Float16* __restrict__ z16,
        const float* __restrict__ We, const float* __restrict__ be,
        const int* __restrict__ row_start,
        const int* __restrict__ srcs, const _Float16* __restrict__ ea16,
        float* __restrict__ hin) {
    int gid = blockIdx.x * 256 + threadIdx.x;
    int node = __builtin_amdgcn_readfirstlane(gid >> 6);
    int lane = threadIdx.x & 63;
    if (node >= N_NODES) return;
    h2 w2[8];
#pragma unroll
    for (int i = 0; i < 8; ++i) {
        h2 t;
        t[0] = (_Float16)We[(2 * i) * 64 + lane];
        t[1] = (_Float16)We[(2 * i + 1) * 64 + lane];
        w2[i] = t;
    }
    float bl = be[lane];
    int p0 = row_start[node], p1 = row_start[node + 1];
    float acc = 0.f;
    int p = p0;
    for (; p + 8 <= p1; p += 8) {
        int s[8];
        float zv[8], ev[8];
#pragma unroll
        for (int u = 0; u < 8; ++u) s[u] = srcs[p + u];
#pragma unroll
        for (int u = 0; u < 8; ++u) zv[u] = (float)z16[(size_t)s[u] * 64 + lane];
#pragma unroll
        for (int u = 0; u < 8; ++u) {
            const uint4* rv = (const uint4*)(ea16 + (size_t)(p + u) * 16);
            uint4 a = rv[0], bq = rv[1];
            float e = bl;
            e = __builtin_amdgcn_fdot2(__builtin_bit_cast(h2, a.x), w2[0], e, false);
            e = __builtin_amdgcn_fdot2(__builtin_bit_cast(h2, a.y), w2[1], e, false);
            e = __builtin_amdgcn_fdot2(__builtin_bit_cast(h2, a.z), w2[2], e, false);
            e = __builtin_amdgcn_fdot2(__builtin_bit_cast(h2, a.w), w2[3], e, false);
            e = __builtin_amdgcn_fdot2(__builtin_bit_cast(h2, bq.x), w2[4], e, false);
            e = __builtin_amdgcn_fdot2(__builtin_bit_cast(h2, bq.y), w2[5], e, false);
            e = __builtin_amdgcn_fdot2(__builtin_bit_cast(h2, bq.z), w2[6], e, false);
            e = __builtin_amdgcn_fdot2(__builtin_bit_cast(h2, bq.w), w2[7], e, false);
            ev[u] = e;
        }
#pragma unroll
        for (int u = 0; u < 8; ++u) acc += fmaxf(zv[u] + ev[u], 0.f);
    }
    for (; p < p1; ++p) {
        int s = srcs[p];
        float zv = (float)z16[(size_t)s * 64 + lane];
        const uint4* rv = (const uint4*)(ea16 + (size_t)p * 16);
        uint4 a = rv[0], bq = rv[1];
        float e = bl;
        e = __builtin_amdgcn_fdot2(__builtin_bit_cast(h2, a.x), w2[0], e, false);
        e = __builtin_amdgcn_fdot2(__builtin_bit_cast(h2, a.y), w2[1], e, false);
        e = __builtin_amdgcn_fdot2(__builtin_bit_cast(h2, a.z), w2[2], e, false);
        e = __builtin_amdgcn_fdot2(__builtin_bit_cast(h2, a.w), w2[3], e, false);
        e = __builtin_amdgcn_fdot2(__builtin_bit_cast(h2, bq.x), w2[4], e, false);
        e = __builtin_amdgcn_fdot2(__builtin_bit_cast(h2, bq.y), w2[5], e, false);
        e = __builtin_amdgcn_fdot2(__builtin_bit_cast(h2, bq.z), w2[6], e, false);
        e = __builtin_amdgcn_fdot2(__builtin_bit_cast(h2, bq.w), w2[7], e, false);
        acc += fmaxf(zv + e, 0.f);
    }
    float zself = zself_base[(size_t)node * zstride + lane];
    hin[(size_t)node * 64 + lane] = zself + acc;
}

// thread-per-node MLP: hout = relu(relu(hin@W1+b1)@W2+b2)
__global__ __launch_bounds__(256) void k_mlp(
        const float* __restrict__ hin,
        const float* __restrict__ W1, const float* __restrict__ b1,
        const float* __restrict__ W2, const float* __restrict__ b2,
        float* __restrict__ hout) {
    int n = blockIdx.x * 256 + threadIdx.x;
    if (n >= N_NODES) return;
    const float4* __restrict__ hv = (const float4*)(hin + (size_t)n * 64);
    float t[64];
#pragma unroll
    for (int j = 0; j < 64; ++j) t[j] = b1[j];
    for (int kc = 0; kc < 16; ++kc) {
        float4 h4v = hv[kc];
        const float* wr = W1 + kc * 4 * 64;
#pragma unroll
        for (int j = 0; j < 64; ++j) t[j] = fmaf(h4v.x, wr[j], t[j]);
#pragma unroll
        for (int j = 0; j < 64; ++j) t[j] = fmaf(h4v.y, wr[64 + j], t[j]);
#pragma unroll
        for (int j = 0; j < 64; ++j) t[j] = fmaf(h4v.z, wr[128 + j], t[j]);
#pragma unroll
        for (int j = 0; j < 64; ++j) t[j] = fmaf(h4v.w, wr[192 + j], t[j]);
    }
#pragma unroll
    for (int j = 0; j < 64; ++j) t[j] = fmaxf(t[j], 0.f);
    float o[64];
#pragma unroll
    for (int j = 0; j < 64; ++j) o[j] = b2[j];
#pragma unroll
    for (int k = 0; k < 64; ++k) {
        const float* wr = W2 + k * 64;
        float tk = t[k];
#pragma unroll
        for (int j = 0; j < 64; ++j) o[j] = fmaf(tk, wr[j], o[j]);
    }
    float4* ov = (float4*)(hout + (size_t)n * 64);
#pragma unroll
    for (int i = 0; i < 16; ++i) {
        float4 v;
        v.x = fmaxf(o[4 * i + 0], 0.f);
        v.y = fmaxf(o[4 * i + 1], 0.f);
        v.z = fmaxf(o[4 * i + 2], 0.f);
        v.w = fmaxf(o[4 * i + 3], 0.f);
        ov[i] = v;
    }
}

// per-channel sum / sumsq over all nodes
__global__ __launch_bounds__(256) void k_stats(const float* __restrict__ h,
                                               float* __restrict__ ssum, float* __restrict__ ssq) {
    __shared__ float ls[64], lq[64];
    int tid = blockIdx.x * 256 + threadIdx.x;
    int nth = gridDim.x * 256;
    float4 s = {0, 0, 0, 0}, q = {0, 0, 0, 0};
    const float4* hv = (const float4*)h;
    for (int i = tid; i < N_NODES * 16; i += nth) {
        float4 v = hv[i];
        s.x += v.x; s.y += v.y; s.z += v.z; s.w += v.w;
        q.x += v.x * v.x; q.y += v.y * v.y; q.z += v.z * v.z; q.w += v.w * v.w;
    }
    if (threadIdx.x < 64) { ls[threadIdx.x] = 0.f; lq[threadIdx.x] = 0.f; }
    __syncthreads();
    int j = (threadIdx.x & 15) * 4;
    atomicAdd(&ls[j + 0], s.x); atomicAdd(&ls[j + 1], s.y);
    atomicAdd(&ls[j + 2], s.z); atomicAdd(&ls[j + 3], s.w);
    atomicAdd(&lq[j + 0], q.x); atomicAdd(&lq[j + 1], q.y);
    atomicAdd(&lq[j + 2], q.z); atomicAdd(&lq[j + 3], q.w);
    __syncthreads();
    if (threadIdx.x < 64) {
        atomicAdd(&ssum[threadIdx.x], ls[threadIdx.x]);
        atomicAdd(&ssq[threadIdx.x], lq[threadIdx.x]);
    }
}

// normalize (BN finalize folded in), write zz slice (stride 192) and optional
// compact f16 copy for the next layer's gather path
__global__ __launch_bounds__(256) void k_norm(const float* __restrict__ h,
        const float* __restrict__ ssum, const float* __restrict__ ssq,
        const float* __restrict__ gamma, const float* __restrict__ beta,
        float* __restrict__ zzslice, _Float16* __restrict__ z16out) {
    int i = blockIdx.x * 256 + threadIdx.x;  // float4 index, N*16 total
    if (i >= N_NODES * 16) return;
    int n = i >> 4, j4 = i & 15;
    int j = j4 * 4;
    float4 v = ((const float4*)h)[i];
    float out[4];
#pragma unroll
    for (int u = 0; u < 4; ++u) {
        float mean = ssum[j + u] * (1.f / N_NODES);
        float var = ssq[j + u] * (1.f / N_NODES) - mean * mean;
        float scale = gamma[j + u] * rsqrtf(var + BN_EPS);
        float shift = beta[j + u] - mean * scale;
        float hv = (u == 0) ? v.x : (u == 1) ? v.y : (u == 2) ? v.z : v.w;
        out[u] = fmaf(hv, scale, shift);
    }
    float4 r = {out[0], out[1], out[2], out[3]};
    *(float4*)(zzslice + (size_t)n * 192 + j4 * 4) = r;
    if (z16out) {
        h4 o = {(_Float16)out[0], (_Float16)out[1], (_Float16)out[2], (_Float16)out[3]};
        ((h4*)(z16out + (size_t)n * 64 + j))[0] = o;
    }
}

// segment-sum over sorted batch: run-length accumulate, atomic per run.
#define GNODES 64
__global__ __launch_bounds__(192) void k_graph(const float* __restrict__ zz,
                                               const int* __restrict__ batch, float* __restrict__ g) {
    int j = threadIdx.x;  // 0..191; 192 floats = exactly one 768B row -> coalesced
    int n0 = blockIdx.x * GNODES;
    int n1 = n0 + GNODES;
    if (n1 > N_NODES) n1 = N_NODES;
    if (n0 >= N_NODES) return;
    float acc = 0.f;
    int cur = batch[n0];
    for (int n = n0; n < n1; ++n) {
        int b = batch[n];
        if (b != cur) {
            atomicAdd(&g[(size_t)cur * 192 + j], acc);
            acc = 0.f;
            cur = b;
        }
        acc += zz[(size_t)n * 192 + j];
    }
    atomicAdd(&g[(size_t)cur * 192 + j], acc);
}

// ---------------- launch ----------------

extern "C" void kernel_launch(void* const* d_in, const int* in_sizes, int n_in,
                              void* d_out, int out_size, void* d_ws, size_t ws_size,
                              hipStream_t stream) {
    const float* x         = (const float*)d_in[0];
    const float* edge_attr = (const float*)d_in[1];
    const float* We        = (const float*)d_in[2];
    const float* be        = (const float*)d_in[3];
    const float* W1        = (const float*)d_in[4];
    const float* b1        = (const float*)d_in[5];
    const float* W2        = (const float*)d_in[6];
    const float* b2        = (const float*)d_in[7];
    const float* gamma     = (const float*)d_in[8];
    const float* beta      = (const float*)d_in[9];
    const int* edge_index  = (const int*)d_in[10];
    const int* batch       = (const int*)d_in[11];

    float* zz = (float*)d_out;
    float* g  = zz + (size_t)N_NODES * 192;

    char* ws = (char*)d_ws;
    size_t off = 0;
    auto alloc = [&](size_t bytes) {
        void* p = ws + off;
        off = (off + bytes + 255) & ~(size_t)255;
        return p;
    };
    int* hist        = (int*)alloc((size_t)N_NODES * 4);
    int* row_start   = (int*)alloc((size_t)(N_NODES + 1) * 4);
    int* partial     = (int*)alloc(64 * 4);
    int* cbase       = (int*)alloc(64 * 4);
    int* bcount      = (int*)alloc((size_t)NBUCK * 4);
    int* bstart      = (int*)alloc((size_t)(NBUCK + 1) * 4);
    int* bcur        = (int*)alloc((size_t)NBUCK * 4);
    int2* brec       = (int2*)alloc((size_t)N_EDGES * 8);          // 12.8 MB
    int* src_sorted  = (int*)alloc((size_t)N_EDGES * 4);           // 6.4 MB
    _Float16* ea16   = (_Float16*)alloc((size_t)N_EDGES * 16 * 2); // 51.2 MB
    _Float16* x16    = (_Float16*)alloc((size_t)N_NODES * 64 * 2); // 12.8 MB
    _Float16* z16    = (_Float16*)alloc((size_t)N_NODES * 64 * 2); // 12.8 MB
    float* hin       = (float*)alloc((size_t)N_NODES * 64 * 4);
    float* hout      = (float*)alloc((size_t)N_NODES * 64 * 4);
    float* ssum      = (float*)alloc((size_t)N_LAYERS * 64 * 4);
    float* ssq       = (float*)alloc((size_t)N_LAYERS * 64 * 4);

    // CSR row_start
    hipMemsetAsync(hist, 0, (size_t)N_NODES * 4, stream);
    hipMemsetAsync(bcount, 0, (size_t)NBUCK * 4, stream);
    k_hist<<<(N_EDGES + 255) / 256, 256, 0, stream>>>(edge_index + N_EDGES, hist);
    k_scan_partial<<<NCHUNK, 256, 0, stream>>>(hist, partial);
    k_scan_base<<<1, 64, 0, stream>>>(partial, cbase);
    k_scan_final<<<NCHUNK, 256, 0, stream>>>(hist, cbase, row_start);

    // bucketed edge sort + fused ea gather/convert
    k_bcount<<<256, 256, 0, stream>>>(edge_index + N_EDGES, bcount);
    k_bscan<<<1, 256, 0, stream>>>(bcount, bstart, bcur);
    k_bscatter<<<(N_EDGES + 255) / 256, 256, 0, stream>>>(edge_index, bcur, brec);
    k_bfinal<<<NBUCK, 256, 0, stream>>>(brec, bstart, row_start, edge_attr, ea16, src_sorted);
    k_cvt_x<<<(N_NODES * 16 + 255) / 256, 256, 0, stream>>>(x, x16);

    hipMemsetAsync(g, 0, (size_t)N_GRAPHS * 192 * 4, stream);
    hipMemsetAsync(ssum, 0, (size_t)N_LAYERS * 64 * 4, stream);
    hipMemsetAsync(ssq, 0, (size_t)N_LAYERS * 64 * 4, stream);

    for (int l = 0; l < N_LAYERS; ++l) {
        const float* zself = (l == 0) ? x : (zz + (size_t)(l - 1) * 64);
        int zstride = (l == 0) ? 64 : 192;
        const _Float16* zsrc16 = (l == 0) ? x16 : z16;
        k_aggregate<<<(N_NODES * 64 + 255) / 256, 256, 0, stream>>>(
            zself, zstride, zsrc16,
            We + (size_t)l * EDGE_DIM * 64, be + (size_t)l * 64,
            row_start, src_sorted, ea16, hin);
        k_mlp<<<(N_NODES + 255) / 256, 256, 0, stream>>>(
            hin, W1 + (size_t)l * 4096, b1 + (size_t)l * 64,
            W2 + (size_t)l * 4096, b2 + (size_t)l * 64, hout);
        k_stats<<<256, 256, 0, stream>>>(hout, ssum + l * 64, ssq + l * 64);
        k_norm<<<(N_NODES * 16 + 255) / 256, 256, 0, stream>>>(
            hout, ssum + l * 64, ssq + l * 64,
            gamma + (size_t)l * 64, beta + (size_t)l * 64,
            zz + (size_t)l * 64, (l < N_LAYERS - 1) ? z16 : (_Float16*)nullptr);
    }
    k_graph<<<(N_NODES + GNODES - 1) / GNODES, 192, 0, stream>>>(zz, batch, g);
}